// Round 8
// baseline (493.171 us; speedup 1.0000x reference)
//
#include <hip/hip_runtime.h>

#define BB 256
#define TT 512
#define CC 128
#define EEXP_OFF 4096    // byte offset of f32 exp(emissions) in d_ws

typedef float f32x4  __attribute__((ext_vector_type(4)));
typedef float f32x16 __attribute__((ext_vector_type(16)));
typedef short short8 __attribute__((ext_vector_type(8)));
typedef short short2v __attribute__((ext_vector_type(2)));

__device__ __forceinline__ unsigned f2bf(float v) {   // f32 -> bf16 bits (RTNE)
    unsigned u = __float_as_uint(v);
    u += 0x7FFFu + ((u >> 16) & 1u);
    return u >> 16;
}
__device__ __forceinline__ unsigned pack2(float a, float b) {
    return f2bf(a) | (f2bf(b) << 16);
}
__device__ __forceinline__ unsigned cvtpk(float lo, float hi) {  // bf16(lo)|bf16(hi)<<16
    unsigned r;
    asm("v_cvt_pk_bf16_f32 %0, %1, %2" : "=v"(r) : "v"(lo), "v"(hi));
    return r;
}
// v_permlane32_swap: x' = [x_lo | y_lo], y' = [x_hi | y_hi]
__device__ __forceinline__ void plswap(unsigned& x, unsigned& y) {
    asm volatile("v_permlane32_swap_b32 %0, %1" : "+v"(x), "+v"(y));
}
__device__ __forceinline__ void mfma_first(f32x16& d, const short8& a, const short8& b,
                                           const f32x16& z) {
    asm("v_mfma_f32_32x32x16_bf16 %0, %1, %2, %3" : "=&v"(d) : "a"(a), "v"(b), "v"(z));
}
__device__ __forceinline__ void mfma_acc(f32x16& d, const short8& a, const short8& b) {
    asm("v_mfma_f32_32x32x16_bf16 %0, %1, %2, %0" : "+v"(d) : "a"(a), "v"(b));
}

// One-time exp(emissions) -> f32 (full precision), memory-bound (~20us).
__global__ __launch_bounds__(256)
void crf_expemit(const float* __restrict__ em, float* __restrict__ ee)
{
    const int i = (blockIdx.x * 256 + threadIdx.x) * 4;
    const f32x4 a = *(const f32x4*)&em[i];
    f32x4 o = {__expf(a[0]), __expf(a[1]), __expf(a[2]), __expf(a[3])};
    *(f32x4*)&ee[i] = o;
}

// Forward algorithm, fully in-register. 8 blocks x 1 wave; wave owns 32
// batches (col = n = lane&31, h = lane>>5). E^T = exp(T)^T lives in 32 AGPR
// A-fragments; alpha in 32 packed-bf16 VGPRs (PK). Per step: 16 permlane
// swaps rebuild B-fragments from PK (the D->B relayout is exactly the
// lane<32/lane>=32 half-swap), 32 MFMAs, f32 emission multiply, repack.
// NO LDS, NO barriers, no cross-wave traffic. Per-batch result captured
// once at t == len-1 (rare divergent branch), so no per-step freeze selects.
template<bool PRE>   // PRE: emx = exp'd f32; else raw f32 (in-loop expf)
__global__ __launch_bounds__(64, 1)
void crf_forward(const float* __restrict__ emx,
                 const void* __restrict__ mask,
                 const float* __restrict__ transitions,
                 float* __restrict__ log_den)
{
    const int l = threadIdx.x;
    const int n = l & 31, h = l >> 5;
    const int b = blockIdx.x * 32 + n;

    // ---- mask dtype + per-batch length (lane counts its half-row) ----
    const unsigned char* mb = (const unsigned char*)mask;
    const bool is_u8 = (mb[1] != 0);   // lengths >= 256 so mask[0][1] is set
    unsigned cnt = 0;
    if (is_u8) {
        const uint4* mp = (const uint4*)(mb + (size_t)b * TT + 256 * h);
        unsigned sa = 0, sb = 0;
        #pragma unroll
        for (int k = 0; k < 8; ++k) {
            const uint4 v = mp[k];
            sa += (v.x & 0x01010101u) + (v.y & 0x01010101u)
                + (v.z & 0x01010101u) + (v.w & 0x01010101u);
        }
        #pragma unroll
        for (int k = 8; k < 16; ++k) {
            const uint4 v = mp[k];
            sb += (v.x & 0x01010101u) + (v.y & 0x01010101u)
                + (v.z & 0x01010101u) + (v.w & 0x01010101u);
        }
        cnt = ((sa * 0x01010101u) >> 24) + ((sb * 0x01010101u) >> 24);
    } else {
        const uint4* mp = (const uint4*)((const unsigned*)mask + (size_t)b * TT + 256 * h);
        #pragma unroll
        for (int k = 0; k < 64; ++k) {
            const uint4 v = mp[k];
            cnt += (v.x ? 1 : 0) + (v.y ? 1 : 0) + (v.z ? 1 : 0) + (v.w ? 1 : 0);
        }
    }
    { unsigned ca = cnt, cb = cnt; plswap(ca, cb); cnt += (h ? ca : cb); }
    const int len_n = (int)cnt;

    // ---- E^T A-fragments -> AGPRs. A[m][k]=exp(T[k][m]); m=32mt+n, k=16kt+8h+e
    short8 afr[4][8];
    #pragma unroll
    for (int mt = 0; mt < 4; ++mt) {
        const int m = 32 * mt + n;
        #pragma unroll
        for (int kt = 0; kt < 8; ++kt) {
            union { short8 s; unsigned u[4]; } fr;
            #pragma unroll
            for (int j = 0; j < 4; ++j) {
                const int k = 16 * kt + 8 * h + 2 * j;
                fr.u[j] = pack2(__expf(transitions[k * CC + m]),
                                __expf(transitions[(k + 1) * CC + m]));
            }
            afr[mt][kt] = fr.s;
        }
    }

    f32x16 z;
    #pragma unroll
    for (int i = 0; i < 16; ++i) z[i] = 0.f;
    asm volatile("" : "+v"(z));

    // ---- t=0: alpha = exp(em0), packed. PK[mt][p] = states (32mt+8(p>>1)+4h+2(p&1), +1)
    const float* emp = emx + (size_t)b * TT * CC + 4 * h;
    unsigned PK[4][8];
    float logoff = 0.f;
    #pragma unroll
    for (int mt = 0; mt < 4; ++mt) {
        f32x16 nv;
        #pragma unroll
        for (int j = 0; j < 4; ++j) {
            const f32x4 v = *(const f32x4*)&emp[32 * mt + 8 * j];
            nv[4*j+0] = v[0]; nv[4*j+1] = v[1]; nv[4*j+2] = v[2]; nv[4*j+3] = v[3];
        }
        if constexpr (!PRE) {
            #pragma unroll
            for (int i = 0; i < 16; ++i) nv[i] = __expf(nv[i]);
        }
        #pragma unroll
        for (int p = 0; p < 8; ++p) PK[mt][p] = cvtpk(nv[2*p], nv[2*p+1]);
    }

    const float* emt = emp + CC;   // time t = 1
    for (int t = 1; t < TT; ++t) {
        // issue emission loads for this step (consumed after MFMA phase)
        f32x16 em[4];
        #pragma unroll
        for (int mt = 0; mt < 4; ++mt) {
            #pragma unroll
            for (int j = 0; j < 4; ++j) {
                const f32x4 v = *(const f32x4*)&emt[32 * mt + 8 * j];
                em[mt][4*j+0] = v[0]; em[mt][4*j+1] = v[1];
                em[mt][4*j+2] = v[2]; em[mt][4*j+3] = v[3];
            }
        }
        emt += CC;

        // renorm factors from OLD alpha (exact power-of-2, per batch)
        const bool rn = ((t & 3) == 0);
        float sc = 1.0f, exl = 0.f;
        if (rn) {
            short2v mx = __builtin_bit_cast(short2v, PK[0][0]);
            #pragma unroll
            for (int mt = 0; mt < 4; ++mt)
                #pragma unroll
                for (int p = 0; p < 8; ++p)
                    if (mt | p)
                        mx = __builtin_elementwise_max(mx, __builtin_bit_cast(short2v, PK[mt][p]));
            unsigned mu = __builtin_bit_cast(unsigned, mx), mv = mu;
            plswap(mu, mv);
            mx = __builtin_elementwise_max(mx, __builtin_bit_cast(short2v, h ? mu : mv));
            const short mm = mx[0] > mx[1] ? mx[0] : mx[1];
            const int ex = (int)(((unsigned short)mm >> 7) & 0xFF) - 127;
            sc = __uint_as_float((unsigned)(127 - ex) << 23);   // 2^-ex
            exl = (float)ex * 0.6931471805599453f;
        }

        // B-fragments from PK via permlane half-swaps (D->B relayout)
        short8 bfr[8];
        #pragma unroll
        for (int kt = 0; kt < 8; ++kt) {
            const int m2 = kt >> 1, k1 = 4 * (kt & 1);
            unsigned x0 = PK[m2][k1 + 0], y0 = PK[m2][k1 + 2];
            unsigned x1 = PK[m2][k1 + 1], y1 = PK[m2][k1 + 3];
            plswap(x0, y0);
            plswap(x1, y1);
            union { short8 s; unsigned u[4]; } bb;
            bb.u[0] = x0; bb.u[1] = x1; bb.u[2] = y0; bb.u[3] = y1;
            bfr[kt] = bb.s;
        }
        // VALU->MFMA read hazard fence on all B-fragments
        asm volatile("s_nop 1"
                     : "+v"(bfr[0]), "+v"(bfr[1]), "+v"(bfr[2]), "+v"(bfr[3]),
                       "+v"(bfr[4]), "+v"(bfr[5]), "+v"(bfr[6]), "+v"(bfr[7]));

        f32x16 a0, a1, a2, a3;
        mfma_first(a0, afr[0][0], bfr[0], z);
        mfma_first(a1, afr[1][0], bfr[0], z);
        mfma_first(a2, afr[2][0], bfr[0], z);
        mfma_first(a3, afr[3][0], bfr[0], z);
        #pragma unroll
        for (int kt = 1; kt < 8; ++kt) {
            mfma_acc(a0, afr[0][kt], bfr[kt]);
            mfma_acc(a1, afr[1][kt], bfr[kt]);
            mfma_acc(a2, afr[2][kt], bfr[kt]);
            mfma_acc(a3, afr[3][kt], bfr[kt]);
        }
        // MFMA->VALU read hazard fence
        asm volatile("s_nop 7\n\ts_nop 7\n\ts_nop 7"
                     : "+v"(a0), "+v"(a1), "+v"(a2), "+v"(a3));

        // epilogue: emission multiply (f32), optional renorm, repack
        if constexpr (!PRE) {
            #pragma unroll
            for (int mt = 0; mt < 4; ++mt)
                #pragma unroll
                for (int i = 0; i < 16; ++i) em[mt][i] = __expf(em[mt][i]);
        }
        f32x16 n0 = a0 * em[0], n1 = a1 * em[1], n2 = a2 * em[2], n3 = a3 * em[3];
        if (rn) { n0 *= sc; n1 *= sc; n2 *= sc; n3 *= sc; logoff += exl; }
        #pragma unroll
        for (int p = 0; p < 8; ++p) {
            PK[0][p] = cvtpk(n0[2*p], n0[2*p+1]);
            PK[1][p] = cvtpk(n1[2*p], n1[2*p+1]);
            PK[2][p] = cvtpk(n2[2*p], n2[2*p+1]);
            PK[3][p] = cvtpk(n3[2*p], n3[2*p+1]);
        }

        // once-per-batch capture of log_den at this batch's last step
        if (t == len_n - 1) {
            const f32x16 sv = (n0 + n1) + (n2 + n3);
            const f32x4 s4 = f32x4{sv[0]+sv[8],  sv[1]+sv[9],  sv[2]+sv[10], sv[3]+sv[11]}
                           + f32x4{sv[4]+sv[12], sv[5]+sv[13], sv[6]+sv[14], sv[7]+sv[15]};
            const float ps = (s4[0]+s4[1]) + (s4[2]+s4[3]);
            unsigned pu = __float_as_uint(ps), qu = pu;
            plswap(pu, qu);
            const float tot = ps + __uint_as_float(h ? pu : qu);
            if (h == 0) log_den[b] = logoff + __logf(tot);
        }
    }
}

__device__ __forceinline__ bool mask_at(const void* mask, bool is_u8, int idx) {
    if (is_u8) return ((const unsigned char*)mask)[idx] != 0;
    return ((const int*)mask)[idx] != 0;
}

// Gold-path score: sum of masked emissions at tags + masked pair transitions.
__global__ __launch_bounds__(256)
void crf_num(const float* __restrict__ em_all,
             const int* __restrict__ tags,
             const void* __restrict__ mask,
             const float* __restrict__ transitions,
             float* __restrict__ log_num)
{
    const int b = blockIdx.x;
    const int j = threadIdx.x;
    const int lane = j & 63;
    const int wid = j >> 6;
    __shared__ float redf[4];

    const unsigned char* mb = (const unsigned char*)mask;
    const bool is_u8 = (mb[1] != 0);

    const float* em = em_all + (size_t)b * TT * CC;
    const int* tg = tags + b * TT;

    float s = 0.f;
    for (int t = j; t < TT; t += 256) {
        if (mask_at(mask, is_u8, b * TT + t)) {
            s += em[t * CC + tg[t]];
            if (t >= 1 && mask_at(mask, is_u8, b * TT + t - 1))
                s += transitions[tg[t - 1] * CC + tg[t]];
        }
    }
    #pragma unroll
    for (int off = 32; off; off >>= 1) s += __shfl_xor(s, off);
    if (lane == 0) redf[wid] = s;
    __syncthreads();
    if (j == 0) log_num[b] = redf[0] + redf[1] + redf[2] + redf[3];
}

__global__ __launch_bounds__(256)
void crf_final(const float* __restrict__ log_den,
               const float* __restrict__ log_num,
               float* __restrict__ out)
{
    const int j = threadIdx.x;   // one thread per batch, B == 256
    const int lane = j & 63;
    const int wid = j >> 6;
    __shared__ float redf[4];
    float v = log_den[j] - log_num[j];
    #pragma unroll
    for (int off = 32; off; off >>= 1) v += __shfl_xor(v, off);
    if (lane == 0) redf[wid] = v;
    __syncthreads();
    if (j == 0) out[0] = (redf[0] + redf[1] + redf[2] + redf[3]) * (1.0f / BB);
}

extern "C" void kernel_launch(void* const* d_in, const int* in_sizes, int n_in,
                              void* d_out, int out_size, void* d_ws, size_t ws_size,
                              hipStream_t stream) {
    const float* emissions   = (const float*)d_in[0];
    const int*   tags        = (const int*)d_in[1];
    const void*  mask        = d_in[2];
    const float* transitions = (const float*)d_in[3];
    float* out = (float*)d_out;

    float* log_den = (float*)d_ws;
    float* log_num = log_den + BB;

    const size_t eexp_bytes = (size_t)BB * TT * CC * 4;
    const bool pre = ws_size >= (size_t)EEXP_OFF + eexp_bytes;

    if (pre) {
        float* eexp = (float*)((char*)d_ws + EEXP_OFF);
        crf_expemit<<<(BB * TT * CC) / 1024, 256, 0, stream>>>(emissions, eexp);
        crf_forward<true><<<BB / 32, 64, 0, stream>>>(eexp, mask, transitions, log_den);
    } else {
        crf_forward<false><<<BB / 32, 64, 0, stream>>>(emissions, mask, transitions, log_den);
    }
    crf_num<<<BB, 256, 0, stream>>>(emissions, tags, mask, transitions, log_num);
    crf_final<<<1, 256, 0, stream>>>(log_den, log_num, out);
}